// Round 6
// baseline (603.505 us; speedup 1.0000x reference)
//
#include <hip/hip_runtime.h>
#include <hip/hip_bf16.h>
#include <stdint.h>

#define N_ROWS 8192
#define DIM    1024
#define BM 256           // block rows (A panel)
#define BN 128           // block cols (B panel)
#define BKF 128          // fp8 bytes of K per tile (= one MFMA K)
#define NT (DIM / BKF)   // 8 K-tiles
#define BUF_SZ 49152u    // per K-tile buffer: A 32 KiB + B 16 KiB

typedef float   f32x4  __attribute__((ext_vector_type(4)));
typedef int     i32x4  __attribute__((ext_vector_type(4)));
typedef int     i32x8  __attribute__((ext_vector_type(8)));

// 16-lane (DPP row) sum via v_add_f32 + row_ror — no LDS traffic.
__device__ __forceinline__ float row_sum16(float x) {
    x += __int_as_float(__builtin_amdgcn_update_dpp(
            0, __float_as_int(x), 0x128 /*row_ror:8*/, 0xf, 0xf, true));
    x += __int_as_float(__builtin_amdgcn_update_dpp(
            0, __float_as_int(x), 0x124 /*row_ror:4*/, 0xf, 0xf, true));
    x += __int_as_float(__builtin_amdgcn_update_dpp(
            0, __float_as_int(x), 0x122 /*row_ror:2*/, 0xf, 0xf, true));
    x += __int_as_float(__builtin_amdgcn_update_dpp(
            0, __float_as_int(x), 0x121 /*row_ror:1*/, 0xf, 0xf, true));
    return x;
}

// ---------------------------------------------------------------------------
// Kernel 1: fused L2-normalize (fp32 -> fp8 e4m3) + fp32 diagonal + S init.
// CHANGED: 1024 blocks x 8 rows (was 8192 x 1) — total-minus-sim is ~80us vs
// a 12.7us BW floor; block-count is the only suspect in this dispatch.
// ---------------------------------------------------------------------------
__global__ __launch_bounds__(256) void nrm_kernel(
    const float* __restrict__ img, const float* __restrict__ txt,
    uint8_t* __restrict__ img_f8, uint8_t* __restrict__ txt_f8,
    float* __restrict__ diag, float* __restrict__ S)
{
    const int t    = threadIdx.x;
    const int lane = t & 63;
    const int w    = t >> 6;
    __shared__ float red[3][4];

#pragma unroll 1
    for (int r = 0; r < 8; ++r) {
        const int row = blockIdx.x * 8 + r;

        const float4 a = ((const float4*)(img + (size_t)row * DIM))[t];
        const float4 b = ((const float4*)(txt + (size_t)row * DIM))[t];

        float sa = a.x * a.x + a.y * a.y + a.z * a.z + a.w * a.w;
        float sb = b.x * b.x + b.y * b.y + b.z * b.z + b.w * b.w;
#pragma unroll
        for (int d = 1; d < 64; d <<= 1) {
            sa += __shfl_xor(sa, d, 64);
            sb += __shfl_xor(sb, d, 64);
        }
        if (lane == 0) { red[0][w] = sa; red[1][w] = sb; }
        __syncthreads();
        sa = red[0][0] + red[0][1] + red[0][2] + red[0][3];
        sb = red[1][0] + red[1][1] + red[1][2] + red[1][3];

        const float ia = 1.0f / fmaxf(sqrtf(sa), 1e-12f);
        const float ib = 1.0f / fmaxf(sqrtf(sb), 1e-12f);

        int ra = 0, rb = 0;
        ra = __builtin_amdgcn_cvt_pk_fp8_f32(a.x * ia, a.y * ia, ra, false);
        ra = __builtin_amdgcn_cvt_pk_fp8_f32(a.z * ia, a.w * ia, ra, true);
        rb = __builtin_amdgcn_cvt_pk_fp8_f32(b.x * ib, b.y * ib, rb, false);
        rb = __builtin_amdgcn_cvt_pk_fp8_f32(b.z * ib, b.w * ib, rb, true);
        ((int*)(img_f8 + (size_t)row * DIM))[t] = ra;
        ((int*)(txt_f8 + (size_t)row * DIM))[t] = rb;

        float dp = (a.x * b.x + a.y * b.y + a.z * b.z + a.w * b.w) * ia * ib;
#pragma unroll
        for (int d = 1; d < 64; d <<= 1) dp += __shfl_xor(dp, d, 64);
        if (lane == 0) red[2][w] = dp;
        __syncthreads();
        if (t == 0) {
            diag[row] = red[2][0] + red[2][1] + red[2][2] + red[2][3];
            S[row] = 0.0f;
        }
    }
}

// ---------------------------------------------------------------------------
// Kernel 2 (REAL, unchanged R5): 256x128 MX-fp8 GEMM, counted vmcnt, triple
// buffer.  This produces the answer; its counters are the primary row.
// ---------------------------------------------------------------------------
__global__ __launch_bounds__(512) void sim_lse_kernel(
    const uint8_t* __restrict__ A, const uint8_t* __restrict__ B,
    float* __restrict__ S)
{
    __shared__ __align__(16) uint8_t smem[3 * BUF_SZ];   // 144 KiB

    const int t     = threadIdx.x;       // 0..511
    const int lane  = t & 63;
    const int w     = t >> 6;            // wave 0..7
    const int waveM = w >> 1;            // 0..3 : 64 rows each
    const int waveN = w & 1;             // 0..1 : 64 cols each
    const int lr    = lane & 15;
    const int q     = lane >> 4;
    const int swz   = lr & 7;

    const int rowA0 = blockIdx.y * BM;
    const int rowB0 = blockIdx.x * BN;
    const uint8_t* Ablk = A + (size_t)rowA0 * DIM;
    const uint8_t* Bblk = B + (size_t)rowB0 * DIM;

    const uint32_t lo_off = (uint32_t)(((2 * q) ^ swz) * 16);

    f32x4 acc[4][4] = {};

    auto stage = [&](int k0, uint32_t base) {
#pragma unroll
        for (int is = 0; is < 4; ++is) {
            const int c   = is * 512 + t;
            const int row = c >> 3;
            const int col = (c & 7) ^ (row & 7);
            __builtin_amdgcn_global_load_lds(
                (const __attribute__((address_space(1))) void*)
                    (Ablk + (size_t)row * DIM + k0 + col * 16),
                (__attribute__((address_space(3))) void*)
                    &smem[base + (uint32_t)c * 16], 16, 0, 0);
        }
#pragma unroll
        for (int is = 0; is < 2; ++is) {
            const int c   = is * 512 + t;
            const int row = c >> 3;
            const int col = (c & 7) ^ (row & 7);
            __builtin_amdgcn_global_load_lds(
                (const __attribute__((address_space(1))) void*)
                    (Bblk + (size_t)row * DIM + k0 + col * 16),
                (__attribute__((address_space(3))) void*)
                    &smem[base + 32768u + (uint32_t)c * 16], 16, 0, 0);
        }
    };

    stage(0,   0u);
    stage(BKF, BUF_SZ);
    asm volatile("s_waitcnt vmcnt(6)" ::: "memory");
    __builtin_amdgcn_s_barrier();

    uint32_t b0 = 0u, b1 = BUF_SZ, b2 = 2u * BUF_SZ;

#pragma unroll 1
    for (int kt = 0; kt < NT; ++kt) {
        if (kt < NT - 2) stage((kt + 2) * BKF, b2);

        i32x8 af[4], bfr[4];
#pragma unroll
        for (int mi = 0; mi < 4; ++mi) {
            const uint8_t* base = &smem[b0 + (uint32_t)((waveM * 64 + mi * 16 + lr) * BKF)];
            i32x4 lo = *(const i32x4*)&base[lo_off];
            i32x4 hi = *(const i32x4*)&base[lo_off ^ 16u];
            af[mi] = (i32x8){lo.x, lo.y, lo.z, lo.w, hi.x, hi.y, hi.z, hi.w};
        }
#pragma unroll
        for (int ni = 0; ni < 4; ++ni) {
            const uint8_t* base = &smem[b0 + 32768u + (uint32_t)((waveN * 64 + ni * 16 + lr) * BKF)];
            i32x4 lo = *(const i32x4*)&base[lo_off];
            i32x4 hi = *(const i32x4*)&base[lo_off ^ 16u];
            bfr[ni] = (i32x8){lo.x, lo.y, lo.z, lo.w, hi.x, hi.y, hi.z, hi.w};
        }
#pragma unroll
        for (int mi = 0; mi < 4; ++mi)
#pragma unroll
            for (int ni = 0; ni < 4; ++ni)
                acc[mi][ni] = __builtin_amdgcn_mfma_scale_f32_16x16x128_f8f6f4(
                    af[mi], bfr[ni], acc[mi][ni], 0, 0, 0, 127, 0, 127);

        if (kt < NT - 2)       asm volatile("s_waitcnt vmcnt(6)" ::: "memory");
        else if (kt == NT - 2) asm volatile("s_waitcnt vmcnt(0)" ::: "memory");
        if (kt < NT - 1) __builtin_amdgcn_s_barrier();

        const uint32_t tmp = b0; b0 = b1; b1 = b2; b2 = tmp;
    }

    const float L2E = 1.44269504088896f;
    const int rowbase = rowA0 + waveM * 64;
#pragma unroll
    for (int mi = 0; mi < 4; ++mi) {
        float p0 = 0.f, p1 = 0.f, p2 = 0.f, p3 = 0.f;
#pragma unroll
        for (int ni = 0; ni < 4; ++ni) {
            p0 += exp2f(acc[mi][ni].x * L2E - L2E);
            p1 += exp2f(acc[mi][ni].y * L2E - L2E);
            p2 += exp2f(acc[mi][ni].z * L2E - L2E);
            p3 += exp2f(acc[mi][ni].w * L2E - L2E);
        }
        p0 = row_sum16(p0); p1 = row_sum16(p1);
        p2 = row_sum16(p2); p3 = row_sum16(p3);
        if ((lane & 15) == 0) {
            float* dst = &S[rowbase + mi * 16 + (lane >> 4) * 4];
            atomicAdd(dst + 0, p0); atomicAdd(dst + 1, p1);
            atomicAdd(dst + 2, p2); atomicAdd(dst + 3, p3);
        }
    }
}

// ---------------------------------------------------------------------------
// ABLATION variants (write to dead scratch Sx; outputs never read).
// MODE 1 = no ds_read (frags synthesized)   -> isolates LDS-read cost
// MODE 2 = no MFMA (frags kept alive w/ asm)-> isolates mfma_scale cost
// MODE 3 = no staging / no vmcnt            -> isolates global->LDS cost
// Barriers kept in ALL modes (skeleton constant).  Rule #17: asm keep-alives
// prevent DCE of the retained pipes.
// ---------------------------------------------------------------------------
template <int MODE>
__device__ __forceinline__ void sim_body_abl(
    const uint8_t* __restrict__ A, const uint8_t* __restrict__ B, float* Sx)
{
    __shared__ __align__(16) uint8_t smem[3 * BUF_SZ];

    const int t     = threadIdx.x;
    const int lane  = t & 63;
    const int w     = t >> 6;
    const int waveM = w >> 1;
    const int waveN = w & 1;
    const int lr    = lane & 15;
    const int q     = lane >> 4;
    const int swz   = lr & 7;

    const int rowA0 = blockIdx.y * BM;
    const int rowB0 = blockIdx.x * BN;
    const uint8_t* Ablk = A + (size_t)rowA0 * DIM;
    const uint8_t* Bblk = B + (size_t)rowB0 * DIM;

    const uint32_t lo_off = (uint32_t)(((2 * q) ^ swz) * 16);

    f32x4 acc[4][4] = {};

    auto stage = [&](int k0, uint32_t base) {
#pragma unroll
        for (int is = 0; is < 4; ++is) {
            const int c   = is * 512 + t;
            const int row = c >> 3;
            const int col = (c & 7) ^ (row & 7);
            __builtin_amdgcn_global_load_lds(
                (const __attribute__((address_space(1))) void*)
                    (Ablk + (size_t)row * DIM + k0 + col * 16),
                (__attribute__((address_space(3))) void*)
                    &smem[base + (uint32_t)c * 16], 16, 0, 0);
        }
#pragma unroll
        for (int is = 0; is < 2; ++is) {
            const int c   = is * 512 + t;
            const int row = c >> 3;
            const int col = (c & 7) ^ (row & 7);
            __builtin_amdgcn_global_load_lds(
                (const __attribute__((address_space(1))) void*)
                    (Bblk + (size_t)row * DIM + k0 + col * 16),
                (__attribute__((address_space(3))) void*)
                    &smem[base + 32768u + (uint32_t)c * 16], 16, 0, 0);
        }
    };

    if constexpr (MODE != 3) {
        stage(0,   0u);
        stage(BKF, BUF_SZ);
        asm volatile("s_waitcnt vmcnt(6)" ::: "memory");
    }
    __builtin_amdgcn_s_barrier();

    uint32_t b0 = 0u, b1 = BUF_SZ, b2 = 2u * BUF_SZ;

#pragma unroll 1
    for (int kt = 0; kt < NT; ++kt) {
        if constexpr (MODE != 3) {
            if (kt < NT - 2) stage((kt + 2) * BKF, b2);
        }

        i32x8 af[4], bfr[4];
        if constexpr (MODE == 1) {
            // synthesized fragments: per-thread, per-kt values (not hoistable)
            const int s = t * 8 + kt;
#pragma unroll
            for (int mi = 0; mi < 4; ++mi)
                af[mi] = (i32x8){s, s + 1, s + 2, s + 3, s + 4, s + 5, s + 6, s + 7};
#pragma unroll
            for (int ni = 0; ni < 4; ++ni)
                bfr[ni] = (i32x8){s + 8, s + 9, s + 10, s + 11, s + 12, s + 13, s + 14, s + 15};
        } else {
#pragma unroll
            for (int mi = 0; mi < 4; ++mi) {
                const uint8_t* base = &smem[b0 + (uint32_t)((waveM * 64 + mi * 16 + lr) * BKF)];
                i32x4 lo = *(const i32x4*)&base[lo_off];
                i32x4 hi = *(const i32x4*)&base[lo_off ^ 16u];
                af[mi] = (i32x8){lo.x, lo.y, lo.z, lo.w, hi.x, hi.y, hi.z, hi.w};
            }
#pragma unroll
            for (int ni = 0; ni < 4; ++ni) {
                const uint8_t* base = &smem[b0 + 32768u + (uint32_t)((waveN * 64 + ni * 16 + lr) * BKF)];
                i32x4 lo = *(const i32x4*)&base[lo_off];
                i32x4 hi = *(const i32x4*)&base[lo_off ^ 16u];
                bfr[ni] = (i32x8){lo.x, lo.y, lo.z, lo.w, hi.x, hi.y, hi.z, hi.w};
            }
        }

        if constexpr (MODE == 2) {
            // keep full-width reads alive, replace MFMA with 2 VALU/tile
#pragma unroll
            for (int mi = 0; mi < 4; ++mi)
                asm volatile("" :: "v"(af[mi]));
#pragma unroll
            for (int ni = 0; ni < 4; ++ni)
                asm volatile("" :: "v"(bfr[ni]));
#pragma unroll
            for (int mi = 0; mi < 4; ++mi)
#pragma unroll
                for (int ni = 0; ni < 4; ++ni)
                    acc[mi][ni].x += (float)af[mi][0] + (float)bfr[ni][0];
        } else {
#pragma unroll
            for (int mi = 0; mi < 4; ++mi)
#pragma unroll
                for (int ni = 0; ni < 4; ++ni)
                    acc[mi][ni] = __builtin_amdgcn_mfma_scale_f32_16x16x128_f8f6f4(
                        af[mi], bfr[ni], acc[mi][ni], 0, 0, 0, 127, 0, 127);
        }

        if constexpr (MODE != 3) {
            if (kt < NT - 2)       asm volatile("s_waitcnt vmcnt(6)" ::: "memory");
            else if (kt == NT - 2) asm volatile("s_waitcnt vmcnt(0)" ::: "memory");
        }
        if (kt < NT - 1) __builtin_amdgcn_s_barrier();

        const uint32_t tmp = b0; b0 = b1; b1 = b2; b2 = tmp;
    }

    const float L2E = 1.44269504088896f;
    const int rowbase = rowA0 + waveM * 64;
#pragma unroll
    for (int mi = 0; mi < 4; ++mi) {
        float p0 = 0.f, p1 = 0.f, p2 = 0.f, p3 = 0.f;
#pragma unroll
        for (int ni = 0; ni < 4; ++ni) {
            p0 += exp2f(acc[mi][ni].x * L2E - L2E);
            p1 += exp2f(acc[mi][ni].y * L2E - L2E);
            p2 += exp2f(acc[mi][ni].z * L2E - L2E);
            p3 += exp2f(acc[mi][ni].w * L2E - L2E);
        }
        p0 = row_sum16(p0); p1 = row_sum16(p1);
        p2 = row_sum16(p2); p3 = row_sum16(p3);
        if ((lane & 15) == 0) {
            float* dst = &Sx[rowbase + mi * 16 + (lane >> 4) * 4];
            atomicAdd(dst + 0, p0); atomicAdd(dst + 1, p1);
            atomicAdd(dst + 2, p2); atomicAdd(dst + 3, p3);
        }
    }
}

__global__ __launch_bounds__(512) void abl_noread_kernel(
    const uint8_t* __restrict__ A, const uint8_t* __restrict__ B, float* Sx)
{ sim_body_abl<1>(A, B, Sx); }

__global__ __launch_bounds__(512) void abl_nomfma_kernel(
    const uint8_t* __restrict__ A, const uint8_t* __restrict__ B, float* Sx)
{ sim_body_abl<2>(A, B, Sx); }

__global__ __launch_bounds__(512) void abl_nostage_kernel(
    const uint8_t* __restrict__ A, const uint8_t* __restrict__ B, float* Sx)
{ sim_body_abl<3>(A, B, Sx); }

// ---------------------------------------------------------------------------
// Kernel 3: out = mean(log(S_i) - diag_i)   UNCHANGED
// ---------------------------------------------------------------------------
__global__ __launch_bounds__(1024) void fin_kernel(
    const float* __restrict__ S, const float* __restrict__ diag,
    float* __restrict__ out)
{
    const int t = threadIdx.x;
    float s = 0.f;
    for (int i = t; i < N_ROWS; i += 1024) s += logf(S[i]) - diag[i];
#pragma unroll
    for (int d = 1; d < 64; d <<= 1) s += __shfl_xor(s, d, 64);
    __shared__ float red[16];
    if ((t & 63) == 0) red[t >> 6] = s;
    __syncthreads();
    if (t == 0) {
        float tot = 0.f;
#pragma unroll
        for (int i = 0; i < 16; ++i) tot += red[i];
        out[0] = tot * (1.0f / N_ROWS);
    }
}

// ---------------------------------------------------------------------------
extern "C" void kernel_launch(void* const* d_in, const int* in_sizes, int n_in,
                              void* d_out, int out_size, void* d_ws, size_t ws_size,
                              hipStream_t stream)
{
    const float* img = (const float*)d_in[0];
    const float* txt = (const float*)d_in[1];
    float* out = (float*)d_out;

    char* ws = (char*)d_ws;
    uint8_t* img_f8 = (uint8_t*)ws;                                  // 8 MiB
    uint8_t* txt_f8 = (uint8_t*)(ws + (size_t)N_ROWS * DIM);         // 8 MiB
    float*   S      = (float*)(ws + (size_t)N_ROWS * DIM * 2);       // 32 KiB
    float*   diag   = S + N_ROWS;                                    // 32 KiB
    float*   Sx     = diag + N_ROWS;                                 // 32 KiB (dead)

    nrm_kernel<<<N_ROWS / 8, 256, 0, stream>>>(img, txt, img_f8, txt_f8, diag, S);
    dim3 grid(N_ROWS / BN, N_ROWS / BM);   // 64 x 32 = 2048 blocks
    sim_lse_kernel<<<grid, 512, 0, stream>>>(img_f8, txt_f8, S);
    fin_kernel<<<1, 1024, 0, stream>>>(S, diag, out);

    // ---- diagnostic ablations (dead output; this round buys information) --
    abl_noread_kernel<<<grid, 512, 0, stream>>>(img_f8, txt_f8, Sx);
    abl_nomfma_kernel<<<grid, 512, 0, stream>>>(img_f8, txt_f8, Sx);
    abl_nostage_kernel<<<grid, 512, 0, stream>>>(img_f8, txt_f8, Sx);
}

// Round 7
// 194.022 us; speedup vs baseline: 3.1105x; 3.1105x over previous
//
#include <hip/hip_runtime.h>
#include <hip/hip_bf16.h>
#include <stdint.h>

#define N_ROWS 8192
#define DIM    1024
#define BM 128
#define BN 128
#define BKF 128            // fp8 bytes of K per tile (= one MFMA K)
#define NT (DIM / BKF)     // 8 K-tiles per C-tile
#define TILES_PB 8         // B-tiles per block (F-amortization)
#define VSTEPS (NT * TILES_PB)   // 64 virtual K-steps per block

typedef float   f32x4  __attribute__((ext_vector_type(4)));
typedef int     i32x4  __attribute__((ext_vector_type(4)));
typedef int     i32x8  __attribute__((ext_vector_type(8)));

// 16-lane (DPP row) sum via v_add_f32 + row_ror — no LDS traffic.
__device__ __forceinline__ float row_sum16(float x) {
    x += __int_as_float(__builtin_amdgcn_update_dpp(
            0, __float_as_int(x), 0x128 /*row_ror:8*/, 0xf, 0xf, true));
    x += __int_as_float(__builtin_amdgcn_update_dpp(
            0, __float_as_int(x), 0x124 /*row_ror:4*/, 0xf, 0xf, true));
    x += __int_as_float(__builtin_amdgcn_update_dpp(
            0, __float_as_int(x), 0x122 /*row_ror:2*/, 0xf, 0xf, true));
    x += __int_as_float(__builtin_amdgcn_update_dpp(
            0, __float_as_int(x), 0x121 /*row_ror:1*/, 0xf, 0xf, true));
    return x;
}

// ---------------------------------------------------------------------------
// Kernel 1: fused L2-normalize (fp32 -> fp8 e4m3) + fp32 diagonal + S init.
// 1024 blocks x 8 rows (R6 version, kept).
// ---------------------------------------------------------------------------
__global__ __launch_bounds__(256) void nrm_kernel(
    const float* __restrict__ img, const float* __restrict__ txt,
    uint8_t* __restrict__ img_f8, uint8_t* __restrict__ txt_f8,
    float* __restrict__ diag, float* __restrict__ S)
{
    const int t    = threadIdx.x;
    const int lane = t & 63;
    const int w    = t >> 6;
    __shared__ float red[3][4];

#pragma unroll 1
    for (int r = 0; r < 8; ++r) {
        const int row = blockIdx.x * 8 + r;

        const float4 a = ((const float4*)(img + (size_t)row * DIM))[t];
        const float4 b = ((const float4*)(txt + (size_t)row * DIM))[t];

        float sa = a.x * a.x + a.y * a.y + a.z * a.z + a.w * a.w;
        float sb = b.x * b.x + b.y * b.y + b.z * b.z + b.w * b.w;
#pragma unroll
        for (int d = 1; d < 64; d <<= 1) {
            sa += __shfl_xor(sa, d, 64);
            sb += __shfl_xor(sb, d, 64);
        }
        if (lane == 0) { red[0][w] = sa; red[1][w] = sb; }
        __syncthreads();
        sa = red[0][0] + red[0][1] + red[0][2] + red[0][3];
        sb = red[1][0] + red[1][1] + red[1][2] + red[1][3];

        const float ia = 1.0f / fmaxf(sqrtf(sa), 1e-12f);
        const float ib = 1.0f / fmaxf(sqrtf(sb), 1e-12f);

        int ra = 0, rb = 0;
        ra = __builtin_amdgcn_cvt_pk_fp8_f32(a.x * ia, a.y * ia, ra, false);
        ra = __builtin_amdgcn_cvt_pk_fp8_f32(a.z * ia, a.w * ia, ra, true);
        rb = __builtin_amdgcn_cvt_pk_fp8_f32(b.x * ib, b.y * ib, rb, false);
        rb = __builtin_amdgcn_cvt_pk_fp8_f32(b.z * ib, b.w * ib, rb, true);
        ((int*)(img_f8 + (size_t)row * DIM))[t] = ra;
        ((int*)(txt_f8 + (size_t)row * DIM))[t] = rb;

        float dp = (a.x * b.x + a.y * b.y + a.z * b.z + a.w * b.w) * ia * ib;
#pragma unroll
        for (int d = 1; d < 64; d <<= 1) dp += __shfl_xor(dp, d, 64);
        if (lane == 0) red[2][w] = dp;
        __syncthreads();
        if (t == 0) {
            diag[row] = red[2][0] + red[2][1] + red[2][2] + red[2][3];
            S[row] = 0.0f;
        }
    }
}

// ---------------------------------------------------------------------------
// Kernel 2: 128x128 MX-fp8 MFMA GEMM, MULTI-TILE BLOCKS (F-amortization).
//   R6 ablations: no single pipe dominates (each removal saves only ~25us);
//   m148 (same structure, 32 kt/block) hit 1628 TF vs our 860 at 8 kt/block
//   => per-block fixed cost F ~ 13.6 steady K-steps (cold pipeline fill +
//   drain + teardown) ~60% of block life.  Fix: each block runs 8 B-tiles
//   against one A-panel in ONE continuous 64-step pipelined loop — prologue
//   paid once per 64 steps, staging never drains at tile boundaries, per-tile
//   epilogue overlaps in-flight staging.  Grid 4096 -> 512 blocks (64 A-
//   panels x 8 B-groups; 2 blocks/CU via 64 KiB LDS; XCD x gets B-group x ->
//   1 MB B slice L2-resident).  Kernel body otherwise VERBATIM R3/R4
//   (verified): 4 waves 2x2, 64x64/wave, dist-1 dbuf, XOR chunk swizzle,
//   DPP row-sum epilogue, atomicAdd row-sums into S.
// ---------------------------------------------------------------------------
__global__ __launch_bounds__(256) void sim_lse_kernel(
    const uint8_t* __restrict__ A, const uint8_t* __restrict__ B,
    float* __restrict__ S)
{
    __shared__ __align__(16) uint8_t smem[2 * 2 * BM * BKF];   // 64 KiB

    const int t     = threadIdx.x;       // 0..255
    const int lane  = t & 63;
    const int w     = t >> 6;            // wave 0..3
    const int waveM = w >> 1;            // 2x2 wave grid, 64x64 each
    const int waveN = w & 1;
    const int lr    = lane & 15;
    const int q     = lane >> 4;
    const int swz   = lr & 7;

    const int rowA0 = blockIdx.y * BM;                    // A panel (0..63)
    const uint8_t* Ablk = A + (size_t)rowA0 * DIM;
    const uint8_t* Bgrp = B + (size_t)blockIdx.x * TILES_PB * BN * DIM;

    const uint32_t lo_off = (uint32_t)(((2 * q) ^ swz) * 16);

    f32x4 acc[4][4] = {};

    // stage virtual step v (tile v>>3, K-slice v&7) into buffer at ldsbase
    auto stage = [&](int v, uint32_t ldsbase) {
        const int k0 = (v & (NT - 1)) * BKF;
        const uint8_t* Bt = Bgrp + (size_t)(v >> 3) * BN * DIM;
#pragma unroll
        for (int is = 0; is < 4; ++is) {
            const int c   = is * 256 + t;        // 16B chunk id, 0..1023
            const int row = c >> 3;              // 0..127
            const int col = (c & 7) ^ (row & 7); // pre-swizzled source chunk
            __builtin_amdgcn_global_load_lds(
                (const __attribute__((address_space(1))) void*)
                    (Ablk + (size_t)row * DIM + k0 + col * 16),
                (__attribute__((address_space(3))) void*)
                    &smem[ldsbase + (uint32_t)c * 16], 16, 0, 0);
            __builtin_amdgcn_global_load_lds(
                (const __attribute__((address_space(1))) void*)
                    (Bt + (size_t)row * DIM + k0 + col * 16),
                (__attribute__((address_space(3))) void*)
                    &smem[ldsbase + 16384u + (uint32_t)c * 16], 16, 0, 0);
        }
    };

    // ---- prologue: ONCE per 64 steps (was once per 8) ---------------------
    stage(0, 0u);
    asm volatile("s_waitcnt vmcnt(0)" ::: "memory");
    __builtin_amdgcn_s_barrier();

    const float L2E = 1.44269504088896f;
    const int rowbase = rowA0 + waveM * 64;

    // ---- main loop: 64 virtual K-steps, continuous pipeline ---------------
#pragma unroll 1
    for (int v = 0; v < VSTEPS; ++v) {
        const uint32_t cur = (uint32_t)((v & 1) << 15);   // 0 / 32768
        const uint32_t nxt = cur ^ 32768u;

        if (v < VSTEPS - 1) stage(v + 1, nxt);   // issue, don't wait

        // Fragments (verified R3/R4 code)
        i32x8 af[4], bfr[4];
#pragma unroll
        for (int mi = 0; mi < 4; ++mi) {
            const uint8_t* base = &smem[cur + (uint32_t)((waveM * 64 + mi * 16 + lr) * BKF)];
            i32x4 lo = *(const i32x4*)&base[lo_off];
            i32x4 hi = *(const i32x4*)&base[lo_off ^ 16u];
            af[mi] = (i32x8){lo.x, lo.y, lo.z, lo.w, hi.x, hi.y, hi.z, hi.w};
        }
#pragma unroll
        for (int ni = 0; ni < 4; ++ni) {
            const uint8_t* base = &smem[cur + 16384u + (uint32_t)((waveN * 64 + ni * 16 + lr) * BKF)];
            i32x4 lo = *(const i32x4*)&base[lo_off];
            i32x4 hi = *(const i32x4*)&base[lo_off ^ 16u];
            bfr[ni] = (i32x8){lo.x, lo.y, lo.z, lo.w, hi.x, hi.y, hi.z, hi.w};
        }
#pragma unroll
        for (int mi = 0; mi < 4; ++mi)
#pragma unroll
            for (int ni = 0; ni < 4; ++ni)
                acc[mi][ni] = __builtin_amdgcn_mfma_scale_f32_16x16x128_f8f6f4(
                    af[mi], bfr[ni], acc[mi][ni],
                    0 /*fmtA=fp8*/, 0 /*fmtB=fp8*/,
                    0, 127 /*scaleA=1.0*/, 0, 127 /*scaleB=1.0*/);

        // tile finished: epilogue (row-sums are column-independent) overlaps
        // the in-flight staging of the next tile's first K-slice.
        if ((v & (NT - 1)) == NT - 1) {
#pragma unroll
            for (int mi = 0; mi < 4; ++mi) {
                float p0 = 0.f, p1 = 0.f, p2 = 0.f, p3 = 0.f;
#pragma unroll
                for (int ni = 0; ni < 4; ++ni) {
                    p0 += exp2f(acc[mi][ni].x * L2E - L2E);
                    p1 += exp2f(acc[mi][ni].y * L2E - L2E);
                    p2 += exp2f(acc[mi][ni].z * L2E - L2E);
                    p3 += exp2f(acc[mi][ni].w * L2E - L2E);
                    acc[mi][ni] = (f32x4){0.f, 0.f, 0.f, 0.f};
                }
                p0 = row_sum16(p0); p1 = row_sum16(p1);
                p2 = row_sum16(p2); p3 = row_sum16(p3);
                if ((lane & 15) == 0) {
                    float* dst = &S[rowbase + mi * 16 + (lane >> 4) * 4];
                    atomicAdd(dst + 0, p0); atomicAdd(dst + 1, p1);
                    atomicAdd(dst + 2, p2); atomicAdd(dst + 3, p3);
                }
            }
        }

        asm volatile("s_waitcnt vmcnt(0)" ::: "memory");
        __builtin_amdgcn_s_barrier();
    }
}

// ---------------------------------------------------------------------------
// Kernel 3: out = mean(log(S_i) - diag_i)   UNCHANGED
// ---------------------------------------------------------------------------
__global__ __launch_bounds__(1024) void fin_kernel(
    const float* __restrict__ S, const float* __restrict__ diag,
    float* __restrict__ out)
{
    const int t = threadIdx.x;
    float s = 0.f;
    for (int i = t; i < N_ROWS; i += 1024) s += logf(S[i]) - diag[i];
#pragma unroll
    for (int d = 1; d < 64; d <<= 1) s += __shfl_xor(s, d, 64);
    __shared__ float red[16];
    if ((t & 63) == 0) red[t >> 6] = s;
    __syncthreads();
    if (t == 0) {
        float tot = 0.f;
#pragma unroll
        for (int i = 0; i < 16; ++i) tot += red[i];
        out[0] = tot * (1.0f / N_ROWS);
    }
}

// ---------------------------------------------------------------------------
extern "C" void kernel_launch(void* const* d_in, const int* in_sizes, int n_in,
                              void* d_out, int out_size, void* d_ws, size_t ws_size,
                              hipStream_t stream)
{
    const float* img = (const float*)d_in[0];
    const float* txt = (const float*)d_in[1];
    float* out = (float*)d_out;

    char* ws = (char*)d_ws;
    uint8_t* img_f8 = (uint8_t*)ws;                                  // 8 MiB
    uint8_t* txt_f8 = (uint8_t*)(ws + (size_t)N_ROWS * DIM);         // 8 MiB
    float*   S      = (float*)(ws + (size_t)N_ROWS * DIM * 2);       // 32 KiB
    float*   diag   = S + N_ROWS;                                    // 32 KiB

    nrm_kernel<<<N_ROWS / 8, 256, 0, stream>>>(img, txt, img_f8, txt_f8, diag, S);
    dim3 grid(N_ROWS / BN / TILES_PB, N_ROWS / BM);   // 8 x 64 = 512 blocks
    sim_lse_kernel<<<grid, 256, 0, stream>>>(img_f8, txt_f8, S);
    fin_kernel<<<1, 1024, 0, stream>>>(S, diag, out);
}

// Round 8
// 193.875 us; speedup vs baseline: 3.1129x; 1.0008x over previous
//
#include <hip/hip_runtime.h>
#include <hip/hip_bf16.h>
#include <stdint.h>

#define N_ROWS 8192
#define DIM    1024
#define BM 128
#define BN 128
#define BKF 128            // fp8 bytes of K per tile (= one MFMA K)
#define NT (DIM / BKF)     // 8 K-tiles per C-tile
#define TILES_PB 8         // B-tiles per block (F-amortization)
#define VSTEPS (NT * TILES_PB)   // 64 virtual K-steps per block

typedef float   f32x4  __attribute__((ext_vector_type(4)));
typedef int     i32x4  __attribute__((ext_vector_type(4)));
typedef int     i32x8  __attribute__((ext_vector_type(8)));

// 16-lane (DPP row) sum via v_add_f32 + row_ror — no LDS traffic.
__device__ __forceinline__ float row_sum16(float x) {
    x += __int_as_float(__builtin_amdgcn_update_dpp(
            0, __float_as_int(x), 0x128 /*row_ror:8*/, 0xf, 0xf, true));
    x += __int_as_float(__builtin_amdgcn_update_dpp(
            0, __float_as_int(x), 0x124 /*row_ror:4*/, 0xf, 0xf, true));
    x += __int_as_float(__builtin_amdgcn_update_dpp(
            0, __float_as_int(x), 0x122 /*row_ror:2*/, 0xf, 0xf, true));
    x += __int_as_float(__builtin_amdgcn_update_dpp(
            0, __float_as_int(x), 0x121 /*row_ror:1*/, 0xf, 0xf, true));
    return x;
}

// ---------------------------------------------------------------------------
// Kernel 1: fused L2-normalize (fp32 -> fp8 e4m3) + fp32 diagonal + S init.
// 1024 blocks x 8 rows.  UNCHANGED from R7.
// ---------------------------------------------------------------------------
__global__ __launch_bounds__(256) void nrm_kernel(
    const float* __restrict__ img, const float* __restrict__ txt,
    uint8_t* __restrict__ img_f8, uint8_t* __restrict__ txt_f8,
    float* __restrict__ diag, float* __restrict__ S)
{
    const int t    = threadIdx.x;
    const int lane = t & 63;
    const int w    = t >> 6;
    __shared__ float red[3][4];

#pragma unroll 1
    for (int r = 0; r < 8; ++r) {
        const int row = blockIdx.x * 8 + r;

        const float4 a = ((const float4*)(img + (size_t)row * DIM))[t];
        const float4 b = ((const float4*)(txt + (size_t)row * DIM))[t];

        float sa = a.x * a.x + a.y * a.y + a.z * a.z + a.w * a.w;
        float sb = b.x * b.x + b.y * b.y + b.z * b.z + b.w * b.w;
#pragma unroll
        for (int d = 1; d < 64; d <<= 1) {
            sa += __shfl_xor(sa, d, 64);
            sb += __shfl_xor(sb, d, 64);
        }
        if (lane == 0) { red[0][w] = sa; red[1][w] = sb; }
        __syncthreads();
        sa = red[0][0] + red[0][1] + red[0][2] + red[0][3];
        sb = red[1][0] + red[1][1] + red[1][2] + red[1][3];

        const float ia = 1.0f / fmaxf(sqrtf(sa), 1e-12f);
        const float ib = 1.0f / fmaxf(sqrtf(sb), 1e-12f);

        int ra = 0, rb = 0;
        ra = __builtin_amdgcn_cvt_pk_fp8_f32(a.x * ia, a.y * ia, ra, false);
        ra = __builtin_amdgcn_cvt_pk_fp8_f32(a.z * ia, a.w * ia, ra, true);
        rb = __builtin_amdgcn_cvt_pk_fp8_f32(b.x * ib, b.y * ib, rb, false);
        rb = __builtin_amdgcn_cvt_pk_fp8_f32(b.z * ib, b.w * ib, rb, true);
        ((int*)(img_f8 + (size_t)row * DIM))[t] = ra;
        ((int*)(txt_f8 + (size_t)row * DIM))[t] = rb;

        float dp = (a.x * b.x + a.y * b.y + a.z * b.z + a.w * b.w) * ia * ib;
#pragma unroll
        for (int d = 1; d < 64; d <<= 1) dp += __shfl_xor(dp, d, 64);
        if (lane == 0) red[2][w] = dp;
        __syncthreads();
        if (t == 0) {
            diag[row] = red[2][0] + red[2][1] + red[2][2] + red[2][3];
            S[row] = 0.0f;
        }
    }
}

// ---------------------------------------------------------------------------
// Kernel 2: 128x128 MX-fp8 GEMM, multi-tile blocks (R7) + LOW-VALU K-step.
//   R7 counters: VALUBusy 55.7% = ~154k cy/CU -- top pipe; MFMA+VALU contend
//   for SIMD issue at 2 waves/SIMD => issue-bound on per-step addr/mov
//   overhead (~125 VALU/step/wave), NOT on any bandwidth.
//   This round: (1) staging addresses held in 8 per-thread pointers advanced
//   by a WAVE-UNIFORM scalar delta per step (+128 | wrap -896 / +130176);
//   (2) ds_read addresses precomputed in 4 VGPRs, buffer toggle = 4 v_xor
//   0x8000, mi*2048 folded into ds imm offsets; (3) frag i32x8 built with
//   __builtin_shufflevector (no element movs).
//   Everything else verbatim R7 (verified): 512 blocks = 8 B-groups x 64
//   A-panels, 64 vsteps, dist-1 dbuf 64 KiB, XOR chunk swizzle, per-tile DPP
//   row-sum epilogue overlapping in-flight staging, atomicAdd into S.
// ---------------------------------------------------------------------------
__global__ __launch_bounds__(256) void sim_lse_kernel(
    const uint8_t* __restrict__ A, const uint8_t* __restrict__ B,
    float* __restrict__ S)
{
    __shared__ __align__(16) uint8_t smem[2 * 2 * BM * BKF];   // 64 KiB

    const int t     = threadIdx.x;       // 0..255
    const int lane  = t & 63;
    const int w     = t >> 6;            // wave 0..3
    const int waveM = w >> 1;            // 2x2 wave grid, 64x64 each
    const int waveN = w & 1;
    const int lr    = lane & 15;
    const int q     = lane >> 4;
    const int swz   = lr & 7;

    const int rowA0 = blockIdx.y * BM;                    // A panel (0..63)
    const uint8_t* Ablk = A + (size_t)rowA0 * DIM;
    const uint8_t* Bgrp = B + (size_t)blockIdx.x * TILES_PB * BN * DIM;

    const uint32_t lo_off = (uint32_t)(((2 * q) ^ swz) * 16);

    // ---- staging pointers: init ONCE for v=0, then uniform-delta advance --
    const uint8_t* pA[4];
    const uint8_t* pB[4];
    uint32_t ldsA[4], ldsB[4];
#pragma unroll
    for (int is = 0; is < 4; ++is) {
        const int c   = is * 256 + t;        // 16B chunk id, 0..1023
        const int row = c >> 3;              // 0..127
        const int col = (c & 7) ^ (row & 7); // pre-swizzled source chunk
        pA[is] = Ablk + (size_t)row * DIM + col * 16;
        pB[is] = Bgrp + (size_t)row * DIM + col * 16;
        ldsA[is] = (uint32_t)c * 16;
        ldsB[is] = 16384u + (uint32_t)c * 16;
    }

    auto stage_inc = [&](uint32_t ldsbase) {
#pragma unroll
        for (int is = 0; is < 4; ++is) {
            __builtin_amdgcn_global_load_lds(
                (const __attribute__((address_space(1))) void*)pA[is],
                (__attribute__((address_space(3))) void*)&smem[ldsbase + ldsA[is]],
                16, 0, 0);
            __builtin_amdgcn_global_load_lds(
                (const __attribute__((address_space(1))) void*)pB[is],
                (__attribute__((address_space(3))) void*)&smem[ldsbase + ldsB[is]],
                16, 0, 0);
        }
    };

    // ---- ds_read address registers (include buffer bit; toggle via XOR) ---
    uint32_t adrA  = (uint32_t)((waveM * 64 + lr) * BKF) + lo_off;
    uint32_t adrAh = (uint32_t)((waveM * 64 + lr) * BKF) + (lo_off ^ 16u);
    uint32_t adrB  = 16384u + (uint32_t)((waveN * 64 + lr) * BKF) + lo_off;
    uint32_t adrBh = 16384u + (uint32_t)((waveN * 64 + lr) * BKF) + (lo_off ^ 16u);

    f32x4 acc[4][4] = {};

    // ---- prologue: stage v=0, advance pointers to v=1, drain once ---------
    stage_inc(0u);
#pragma unroll
    for (int is = 0; is < 4; ++is) { pA[is] += 128; pB[is] += 128; }
    asm volatile("s_waitcnt vmcnt(0)" ::: "memory");
    __builtin_amdgcn_s_barrier();

    const float L2E = 1.44269504088896f;
    const int rowbase = rowA0 + waveM * 64;

    // ---- main loop: 64 virtual K-steps, continuous pipeline ---------------
#pragma unroll 1
    for (int v = 0; v < VSTEPS; ++v) {
        const uint32_t nxt = (uint32_t)(((v & 1) ^ 1) << 15);

        if (v < VSTEPS - 1) {
            stage_inc(nxt);                       // issue, don't wait
            // advance pointers to stage-target v+2 (uniform scalar delta)
            const bool wrap = ((v + 1) & (NT - 1)) == (NT - 1);
            const int dA = wrap ? -(BKF * (NT - 1)) : BKF;              // -896 | +128
            const int dB = wrap ? (BN * DIM - BKF * (NT - 1)) : BKF;    // +130176 | +128
#pragma unroll
            for (int is = 0; is < 4; ++is) { pA[is] += dA; pB[is] += dB; }
        }

        // Fragments: addresses live in 4 VGPRs; mi/ni*2048 folds into ds imm.
        i32x8 af[4], bfr[4];
#pragma unroll
        for (int mi = 0; mi < 4; ++mi) {
            i32x4 lo = *(const i32x4*)&smem[adrA  + mi * 2048];
            i32x4 hi = *(const i32x4*)&smem[adrAh + mi * 2048];
            af[mi] = __builtin_shufflevector(lo, hi, 0, 1, 2, 3, 4, 5, 6, 7);
        }
#pragma unroll
        for (int ni = 0; ni < 4; ++ni) {
            i32x4 lo = *(const i32x4*)&smem[adrB  + ni * 2048];
            i32x4 hi = *(const i32x4*)&smem[adrBh + ni * 2048];
            bfr[ni] = __builtin_shufflevector(lo, hi, 0, 1, 2, 3, 4, 5, 6, 7);
        }
#pragma unroll
        for (int mi = 0; mi < 4; ++mi)
#pragma unroll
            for (int ni = 0; ni < 4; ++ni)
                acc[mi][ni] = __builtin_amdgcn_mfma_scale_f32_16x16x128_f8f6f4(
                    af[mi], bfr[ni], acc[mi][ni],
                    0 /*fmtA=fp8*/, 0 /*fmtB=fp8*/,
                    0, 127 /*scaleA=1.0*/, 0, 127 /*scaleB=1.0*/);

        // toggle read buffer (4 v_xor)
        adrA ^= 32768u; adrAh ^= 32768u; adrB ^= 32768u; adrBh ^= 32768u;

        // tile finished: epilogue (row-sum only, column-independent) overlaps
        // the in-flight staging of the next tile's first K-slice.
        if ((v & (NT - 1)) == NT - 1) {
#pragma unroll
            for (int mi = 0; mi < 4; ++mi) {
                float p0 = 0.f, p1 = 0.f, p2 = 0.f, p3 = 0.f;
#pragma unroll
                for (int ni = 0; ni < 4; ++ni) {
                    p0 += exp2f(acc[mi][ni].x * L2E - L2E);
                    p1 += exp2f(acc[mi][ni].y * L2E - L2E);
                    p2 += exp2f(acc[mi][ni].z * L2E - L2E);
                    p3 += exp2f(acc[mi][ni].w * L2E - L2E);
                    acc[mi][ni] = (f32x4){0.f, 0.f, 0.f, 0.f};
                }
                p0 = row_sum16(p0); p1 = row_sum16(p1);
                p2 = row_sum16(p2); p3 = row_sum16(p3);
                if ((lane & 15) == 0) {
                    float* dst = &S[rowbase + mi * 16 + (lane >> 4) * 4];
                    atomicAdd(dst + 0, p0); atomicAdd(dst + 1, p1);
                    atomicAdd(dst + 2, p2); atomicAdd(dst + 3, p3);
                }
            }
        }

        asm volatile("s_waitcnt vmcnt(0)" ::: "memory");
        __builtin_amdgcn_s_barrier();
    }
}

// ---------------------------------------------------------------------------
// Kernel 3: out = mean(log(S_i) - diag_i)   UNCHANGED
// ---------------------------------------------------------------------------
__global__ __launch_bounds__(1024) void fin_kernel(
    const float* __restrict__ S, const float* __restrict__ diag,
    float* __restrict__ out)
{
    const int t = threadIdx.x;
    float s = 0.f;
    for (int i = t; i < N_ROWS; i += 1024) s += logf(S[i]) - diag[i];
#pragma unroll
    for (int d = 1; d < 64; d <<= 1) s += __shfl_xor(s, d, 64);
    __shared__ float red[16];
    if ((t & 63) == 0) red[t >> 6] = s;
    __syncthreads();
    if (t == 0) {
        float tot = 0.f;
#pragma unroll
        for (int i = 0; i < 16; ++i) tot += red[i];
        out[0] = tot * (1.0f / N_ROWS);
    }
}

// ---------------------------------------------------------------------------
extern "C" void kernel_launch(void* const* d_in, const int* in_sizes, int n_in,
                              void* d_out, int out_size, void* d_ws, size_t ws_size,
                              hipStream_t stream)
{
    const float* img = (const float*)d_in[0];
    const float* txt = (const float*)d_in[1];
    float* out = (float*)d_out;

    char* ws = (char*)d_ws;
    uint8_t* img_f8 = (uint8_t*)ws;                                  // 8 MiB
    uint8_t* txt_f8 = (uint8_t*)(ws + (size_t)N_ROWS * DIM);         // 8 MiB
    float*   S      = (float*)(ws + (size_t)N_ROWS * DIM * 2);       // 32 KiB
    float*   diag   = S + N_ROWS;                                    // 32 KiB

    nrm_kernel<<<N_ROWS / 8, 256, 0, stream>>>(img, txt, img_f8, txt_f8, diag, S);
    dim3 grid(N_ROWS / BN / TILES_PB, N_ROWS / BM);   // 8 x 64 = 512 blocks
    sim_lse_kernel<<<grid, 256, 0, stream>>>(img_f8, txt_f8, S);
    fin_kernel<<<1, 1024, 0, stream>>>(S, diag, out);
}